// Round 2
// baseline (226.645 us; speedup 1.0000x reference)
//
#include <hip/hip_runtime.h>
#include <hip/hip_bf16.h>
#include <stdint.h>

#define NN 100000
#define EE 1600000
#define ALPHA 0.2f
#define MM_BLOCKS 1563  // ceil(400000/256)

typedef __bf16 bf16_t;
typedef __bf16 bf16x8 __attribute__((ext_vector_type(8)));
typedef __bf16 bf16x4 __attribute__((ext_vector_type(4)));
typedef float fx4 __attribute__((ext_vector_type(4)));

// ---- workspace layout (bytes) ----
// Wtab    @ 0         : 4096 uint4 (64 KB) frag-major bf16 W0|W1 table
// F1      @ 65536     : 100000*128 bf16     = 25600000
// s0      @ 25665536  : 100000*4  f32       = 1600000
// s1      @ 27265536  : 100000*4  f32       = 1600000
// mma     @ 28865536  : 8 uint slots, 64B-strided (512 B) — atomic min/max keys

// Order-preserving float<->uint key: uint compare order == float order.
__device__ __forceinline__ unsigned fkey(float f) {
  unsigned u = __float_as_uint(f);
  return u ^ (0x80000000u | (unsigned)((int)u >> 31));
}
__device__ __forceinline__ float fdec(unsigned k) {
  unsigned u = (k & 0x80000000u) ? (k ^ 0x80000000u) : ~k;
  return __uint_as_float(u);
}

// One-shot: build the fragment-major lane-linear bf16 W table in global WS.
// task: ct=task>>8, ks=(task>>6)&3, l=task&63; W row = ct*16+(l&15),
// float col0 = (ks*4+(l>>4))*8.  Wtab[task] = 8 bf16 (16 B).
// Also initializes the 8 atomic min/max slots (stream-ordered before minmax1).
__global__ __launch_bounds__(512) void wconv_kernel(
    const float* __restrict__ W0, const float* __restrict__ W1,
    uint4* __restrict__ Wtab, unsigned* __restrict__ mma)
{
  const int task = blockIdx.x * 512 + threadIdx.x;
  if (blockIdx.x == 0 && threadIdx.x < 8)
    mma[threadIdx.x * 16] = (threadIdx.x < 4) ? 0u : 0xFFFFFFFFu;
  if (task >= 4096) return;
  const int sct = task >> 8, sks = (task >> 6) & 3, sl = task & 63;
  const int r  = sct * 16 + (sl & 15);
  const int c0 = (sks * 4 + (sl >> 4)) * 8;
  const float* src = (r < 128 ? W0 + (size_t)r * 128 : W1 + (size_t)(r - 128) * 128) + c0;
  const fx4 wa = *(const fx4*)src;
  const fx4 wb = *(const fx4*)(src + 4);
  bf16x8 wf;
  wf[0] = (bf16_t)wa[0]; wf[1] = (bf16_t)wa[1];
  wf[2] = (bf16_t)wa[2]; wf[3] = (bf16_t)wa[3];
  wf[4] = (bf16_t)wb[0]; wf[5] = (bf16_t)wb[1];
  wf[6] = (bf16_t)wb[2]; wf[7] = (bf16_t)wb[3];
  Wtab[task] = __builtin_bit_cast(uint4, wf);
}

// One wave per 16-node tile, 8 tiles per 512-thread block. Whole 64 KB bf16
// W table async-DMA'd into LDS (global_load_lds, 16 B/lane, lane-linear —
// no VALU, no VGPR round-trip). Per-wave VMEM: 8 X loads.
// D[ch][node] = leaky(W_ch . X_node) via mfma(wf, xf); ch=ct*16+quad*4+r,
// node=n0+col. 64 KB LDS + 512 thr -> 2 blocks/CU = 16 waves/CU.
__global__ __launch_bounds__(512) void gemm_kernel(
    const float* __restrict__ X, const uint4* __restrict__ Wtab,
    const float* __restrict__ a0,
    bf16_t* __restrict__ F1, float* __restrict__ s0g, float* __restrict__ s1g)
{
  __shared__ uint4 lw[4096];  // 64 KB
  const int tid  = threadIdx.x;
  const int wv   = tid >> 6;
  const int lane = tid & 63;
  const int col  = lane & 15;
  const int quad = lane >> 4;

  // Async-stage the precomputed table: per wave, dest = uniform base +
  // lane*16 which matches task = i*512 + wv*64 + lane exactly.
#pragma unroll
  for (int i = 0; i < 8; ++i) {
    const int task = i * 512 + tid;
    __builtin_amdgcn_global_load_lds(
        (const __attribute__((address_space(1))) uint32_t*)(Wtab + task),
        (__attribute__((address_space(3))) uint32_t*)(&lw[task]), 16, 0, 0);
  }
  __syncthreads();  // emits s_waitcnt vmcnt(0) before s_barrier -> DMA done

  const int tile = blockIdx.x * 8 + wv;
  if (tile >= (NN / 16)) return;
  const int n0   = tile * 16;
  const int node = n0 + col;

  fx4 acc[16];
#pragma unroll
  for (int c = 0; c < 16; ++c) {
    acc[c][0] = 0.f; acc[c][1] = 0.f; acc[c][2] = 0.f; acc[c][3] = 0.f;
  }

  const float* xrow = X + (size_t)node * 128 + quad * 8;
#pragma unroll
  for (int ks = 0; ks < 4; ++ks) {
    fx4 xa = *(const fx4*)(xrow + ks * 32);
    fx4 xb = *(const fx4*)(xrow + ks * 32 + 4);
    bf16x8 xf;
    xf[0] = (bf16_t)xa[0]; xf[1] = (bf16_t)xa[1];
    xf[2] = (bf16_t)xa[2]; xf[3] = (bf16_t)xa[3];
    xf[4] = (bf16_t)xb[0]; xf[5] = (bf16_t)xb[1];
    xf[6] = (bf16_t)xb[2]; xf[7] = (bf16_t)xb[3];
#pragma unroll
    for (int ct = 0; ct < 16; ++ct) {
      const uint4 w4 = lw[(ct * 4 + ks) * 64 + lane];
      const bf16x8 wf = __builtin_bit_cast(bf16x8, w4);
      acc[ct] = __builtin_amdgcn_mfma_f32_16x16x32_bf16(wf, xf, acc[ct], 0, 0, 0);
    }
  }

  float sdot[8];
#pragma unroll
  for (int s = 0; s < 8; ++s) sdot[s] = 0.f;

#pragma unroll
  for (int ct = 0; ct < 16; ++ct) {
    const fx4 av = *(const fx4*)(a0 + (ct & 7) * 16 + quad * 4);
#pragma unroll
    for (int r = 0; r < 4; ++r) {
      float v = acc[ct][r];
      v = v > 0.f ? v : ALPHA * v;
      acc[ct][r] = v;
      sdot[ct >> 1] += v * av[r];
    }
    if (ct >= 8) {
      bf16x4 p;
      p[0] = (bf16_t)acc[ct][0]; p[1] = (bf16_t)acc[ct][1];
      p[2] = (bf16_t)acc[ct][2]; p[3] = (bf16_t)acc[ct][3];
      *(bf16x4*)(F1 + (size_t)node * 128 + (ct - 8) * 16 + quad * 4) = p;
    }
  }

#pragma unroll
  for (int s = 0; s < 8; ++s) {
    sdot[s] += __shfl_xor(sdot[s], 16);
    sdot[s] += __shfl_xor(sdot[s], 32);
  }
  if (quad == 0) {
    fx4 r0, r1;
    r0[0] = sdot[0]; r0[1] = sdot[1]; r0[2] = sdot[2]; r0[3] = sdot[3];
    r1[0] = sdot[4]; r1[1] = sdot[5]; r1[2] = sdot[6]; r1[3] = sdot[7];
    *(fx4*)(s0g + (size_t)node * 4) = r0;
    *(fx4*)(s1g + (size_t)node * 4) = r1;
  }
}

// Stage 1: per-head min/max of att = s0[src] + s1[col]; one thread per 4
// edges (400k threads), block-level reduction, then 8 device-scope atomics
// per block onto 64B-strided order-preserving uint keys (no stage-2 kernel).
__global__ __launch_bounds__(256) void minmax1_kernel(
    const int* __restrict__ cidx, const float* __restrict__ s0g,
    const float* __restrict__ s1g, unsigned* __restrict__ mma)
{
  __shared__ float s_red[4][8];
  const int t = blockIdx.x * 256 + threadIdx.x;
  fx4 mx, mn;
#pragma unroll
  for (int h = 0; h < 4; ++h) { mx[h] = -1e30f; mn[h] = 1e30f; }
  if (t < EE / 4) {
    const int node = t >> 2;  // edges 4t..4t+3 all have src = t>>2
    const fx4 s0v = *(const fx4*)(s0g + (size_t)node * 4);
    const int4 c4 = ((const int4*)cidx)[t];
    const int cc[4] = {c4.x, c4.y, c4.z, c4.w};
#pragma unroll
    for (int j = 0; j < 4; ++j) {
      const fx4 s1v = *(const fx4*)(s1g + (size_t)cc[j] * 4);
#pragma unroll
      for (int h = 0; h < 4; ++h) {
        const float att = s0v[h] + s1v[h];
        mx[h] = fmaxf(mx[h], att);
        mn[h] = fminf(mn[h], att);
      }
    }
  }
#pragma unroll
  for (int off = 1; off < 64; off <<= 1) {
#pragma unroll
    for (int h = 0; h < 4; ++h) {
      mx[h] = fmaxf(mx[h], __shfl_xor(mx[h], off));
      mn[h] = fminf(mn[h], __shfl_xor(mn[h], off));
    }
  }
  const int wv = threadIdx.x >> 6;
  if ((threadIdx.x & 63) == 0) {
#pragma unroll
    for (int h = 0; h < 4; ++h) {
      s_red[wv][h] = mx[h];
      s_red[wv][4 + h] = mn[h];
    }
  }
  __syncthreads();
  if (threadIdx.x < 8) {
    const int s = threadIdx.x;
    float v = s_red[0][s];
    if (s < 4) {
      v = fmaxf(v, s_red[1][s]); v = fmaxf(v, s_red[2][s]); v = fmaxf(v, s_red[3][s]);
      atomicMax(&mma[s * 16], fkey(v));
    } else {
      v = fminf(v, s_red[1][s]); v = fminf(v, s_red[2][s]); v = fminf(v, s_red[3][s]);
      atomicMin(&mma[s * 16], fkey(v));
    }
  }
}

// Per node: weighted aggregation of 16 neighbor F1 rows.
// 16 lanes per node; lane covers 8 consecutive dims (bf16x8 = 16B loads).
// FORCED MLP: all 16 s1 gathers + all 16 F1 row gathers issued in one
// region, then sched_barrier(0) fences the scheduler so it cannot sink
// loads into the consume loop (R1 showed it re-serializes otherwise:
// VGPR stayed 36). Expect VGPR ~110-130, ~32 VMEM in flight per thread.
__global__ __launch_bounds__(256) void aggregate_kernel(
    const int* __restrict__ cidx, const float* __restrict__ s0g,
    const float* __restrict__ s1g, const bf16_t* __restrict__ F1,
    const unsigned* __restrict__ mma, float* __restrict__ out)
{
  const int t = blockIdx.x * 256 + threadIdx.x;
  const int node = t >> 4;
  if (node >= NN) return;
  const int sub = t & 15;
  const int h = sub >> 2;
  const float mxv = fdec(mma[h * 16]);
  const float mnv = fdec(mma[(4 + h) * 16]);
  const float scale = 1.f / (mxv - mnv);
  const float s0v = s0g[node * 4 + h];
  float a_[8] = {0.f, 0.f, 0.f, 0.f, 0.f, 0.f, 0.f, 0.f};
  float wsum = 0.f;

  const int4* ce4 = (const int4*)(cidx + (size_t)node * 16);
  const int4 c01 = ce4[0], c23 = ce4[1], c45 = ce4[2], c67 = ce4[3];
  const int cc[16] = {c01.x, c01.y, c01.z, c01.w, c23.x, c23.y, c23.z, c23.w,
                      c45.x, c45.y, c45.z, c45.w, c67.x, c67.y, c67.z, c67.w};

  float s1v[16];
  bf16x8 f[16];
#pragma unroll
  for (int j = 0; j < 16; ++j) {
    const int c = cc[j];
    s1v[j] = s1g[(size_t)c * 4 + h];
    f[j] = *(const bf16x8*)(F1 + (size_t)c * 128 + sub * 8);
  }
  __builtin_amdgcn_sched_barrier(0);  // loads may not sink below this point

#pragma unroll
  for (int j = 0; j < 16; ++j) {
    const float w = __expf((s0v + s1v[j] - mnv) * scale);
    wsum += w;
#pragma unroll
    for (int k = 0; k < 8; ++k) a_[k] += w * (float)f[j][k];
  }

  const float inv = 1.f / wsum;
  fx4 r0, r1;
#pragma unroll
  for (int j = 0; j < 4; ++j) { r0[j] = a_[j] * inv; r1[j] = a_[4 + j] * inv; }
  float* op = out + (size_t)node * 128 + sub * 8;
  *(fx4*)op = r0;
  *(fx4*)(op + 4) = r1;
}

extern "C" void kernel_launch(void* const* d_in, const int* in_sizes, int n_in,
                              void* d_out, int out_size, void* d_ws, size_t ws_size,
                              hipStream_t stream)
{
  const float* X   = (const float*)d_in[0];
  const float* W0  = (const float*)d_in[1];
  const float* W1  = (const float*)d_in[2];
  const float* a0  = (const float*)d_in[3];
  // d_in[4] = edge_src: structurally repeat(arange(N),16); use e>>4 instead.
  const int* cidx  = (const int*)d_in[5];
  char* ws = (char*)d_ws;
  uint4*    Wtab    = (uint4*)ws;
  bf16_t*   F1      = (bf16_t*)(ws + 65536);
  float*    s0g     = (float*)(ws + 25665536);
  float*    s1g     = (float*)(ws + 27265536);
  unsigned* mma     = (unsigned*)(ws + 28865536);
  float*    out     = (float*)d_out;

  wconv_kernel<<<8, 512, 0, stream>>>(W0, W1, Wtab, mma);
  gemm_kernel<<<782, 512, 0, stream>>>(X, Wtab, a0, F1, s0g, s1g);
  minmax1_kernel<<<MM_BLOCKS, 256, 0, stream>>>(cidx, s0g, s1g, mma);
  aggregate_kernel<<<6250, 256, 0, stream>>>(cidx, s0g, s1g, F1, mma, out);
}

// Round 3
// 212.202 us; speedup vs baseline: 1.0681x; 1.0681x over previous
//
#include <hip/hip_runtime.h>
#include <hip/hip_bf16.h>
#include <stdint.h>

#define NN 100000
#define EE 1600000
#define ALPHA 0.2f
#define MM_BLOCKS 1563  // ceil(400000/256)

typedef __bf16 bf16_t;
typedef __bf16 bf16x8 __attribute__((ext_vector_type(8)));
typedef __bf16 bf16x4 __attribute__((ext_vector_type(4)));
typedef float fx4 __attribute__((ext_vector_type(4)));

// ---- workspace layout (bytes) ----
// Wtab    @ 0         : 4096 uint4 (64 KB) frag-major bf16 W0|W1 table
// F1      @ 65536     : 100000*128 bf16     = 25600000
// s0      @ 25665536  : 100000*4  f32       = 1600000
// s1      @ 27265536  : 100000*4  f32       = 1600000
// mm      @ 28865536  : 8 f32 (mx[4], mn[4])
// partial @ 28865600  : MM_BLOCKS*8 f32     = 50016

// One-shot: build the fragment-major lane-linear bf16 W table in global WS.
// task: ct=task>>8, ks=(task>>6)&3, l=task&63; W row = ct*16+(l&15),
// float col0 = (ks*4+(l>>4))*8.  Wtab[task] = 8 bf16 (16 B).
__global__ __launch_bounds__(512) void wconv_kernel(
    const float* __restrict__ W0, const float* __restrict__ W1,
    uint4* __restrict__ Wtab)
{
  const int task = blockIdx.x * 512 + threadIdx.x;
  if (task >= 4096) return;
  const int sct = task >> 8, sks = (task >> 6) & 3, sl = task & 63;
  const int r  = sct * 16 + (sl & 15);
  const int c0 = (sks * 4 + (sl >> 4)) * 8;
  const float* src = (r < 128 ? W0 + (size_t)r * 128 : W1 + (size_t)(r - 128) * 128) + c0;
  const fx4 wa = *(const fx4*)src;
  const fx4 wb = *(const fx4*)(src + 4);
  bf16x8 wf;
  wf[0] = (bf16_t)wa[0]; wf[1] = (bf16_t)wa[1];
  wf[2] = (bf16_t)wa[2]; wf[3] = (bf16_t)wa[3];
  wf[4] = (bf16_t)wb[0]; wf[5] = (bf16_t)wb[1];
  wf[6] = (bf16_t)wb[2]; wf[7] = (bf16_t)wb[3];
  Wtab[task] = __builtin_bit_cast(uint4, wf);
}

// One wave per 16-node tile, 8 tiles per 512-thread block, 2 tiles per wave
// (grid-stride) so the 64 KB LDS staging is amortized over 2x the compute.
// Whole bf16 W table async-DMA'd into LDS (global_load_lds, 16 B/lane,
// lane-linear). D[ch][node] = leaky(W_ch . X_node) via mfma(wf, xf);
// ch=ct*16+quad*4+r, node=n0+col. 64 KB LDS + 512 thr -> 2 blocks/CU.
#define GEMM_BLOCKS 391  // 391*8 = 3128 waves; 2 tiles/wave covers 6250 tiles
__global__ __launch_bounds__(512) void gemm_kernel(
    const float* __restrict__ X, const uint4* __restrict__ Wtab,
    const float* __restrict__ a0,
    bf16_t* __restrict__ F1, float* __restrict__ s0g, float* __restrict__ s1g)
{
  __shared__ uint4 lw[4096];  // 64 KB
  const int tid  = threadIdx.x;
  const int wv   = tid >> 6;
  const int lane = tid & 63;
  const int col  = lane & 15;
  const int quad = lane >> 4;

  // Async-stage the precomputed table: per wave, dest = uniform base +
  // lane*16 which matches task = i*512 + wv*64 + lane exactly.
#pragma unroll
  for (int i = 0; i < 8; ++i) {
    const int task = i * 512 + tid;
    __builtin_amdgcn_global_load_lds(
        (const __attribute__((address_space(1))) uint32_t*)(Wtab + task),
        (__attribute__((address_space(3))) uint32_t*)(&lw[task]), 16, 0, 0);
  }
  __syncthreads();  // emits s_waitcnt vmcnt(0) before s_barrier -> DMA done

#pragma unroll 1
  for (int tt = 0; tt < 2; ++tt) {
    const int tile = blockIdx.x * 8 + wv + tt * (GEMM_BLOCKS * 8);
    if (tile >= (NN / 16)) continue;
    const int n0   = tile * 16;
    const int node = n0 + col;

    fx4 acc[16];
#pragma unroll
    for (int c = 0; c < 16; ++c) {
      acc[c][0] = 0.f; acc[c][1] = 0.f; acc[c][2] = 0.f; acc[c][3] = 0.f;
    }

    const float* xrow = X + (size_t)node * 128 + quad * 8;
#pragma unroll
    for (int ks = 0; ks < 4; ++ks) {
      fx4 xa = *(const fx4*)(xrow + ks * 32);
      fx4 xb = *(const fx4*)(xrow + ks * 32 + 4);
      bf16x8 xf;
      xf[0] = (bf16_t)xa[0]; xf[1] = (bf16_t)xa[1];
      xf[2] = (bf16_t)xa[2]; xf[3] = (bf16_t)xa[3];
      xf[4] = (bf16_t)xb[0]; xf[5] = (bf16_t)xb[1];
      xf[6] = (bf16_t)xb[2]; xf[7] = (bf16_t)xb[3];
#pragma unroll
      for (int ct = 0; ct < 16; ++ct) {
        const uint4 w4 = lw[(ct * 4 + ks) * 64 + lane];
        const bf16x8 wf = __builtin_bit_cast(bf16x8, w4);
        acc[ct] = __builtin_amdgcn_mfma_f32_16x16x32_bf16(wf, xf, acc[ct], 0, 0, 0);
      }
    }

    float sdot[8];
#pragma unroll
    for (int s = 0; s < 8; ++s) sdot[s] = 0.f;

#pragma unroll
    for (int ct = 0; ct < 16; ++ct) {
      const fx4 av = *(const fx4*)(a0 + (ct & 7) * 16 + quad * 4);
#pragma unroll
      for (int r = 0; r < 4; ++r) {
        float v = acc[ct][r];
        v = v > 0.f ? v : ALPHA * v;
        acc[ct][r] = v;
        sdot[ct >> 1] += v * av[r];
      }
      if (ct >= 8) {
        bf16x4 p;
        p[0] = (bf16_t)acc[ct][0]; p[1] = (bf16_t)acc[ct][1];
        p[2] = (bf16_t)acc[ct][2]; p[3] = (bf16_t)acc[ct][3];
        *(bf16x4*)(F1 + (size_t)node * 128 + (ct - 8) * 16 + quad * 4) = p;
      }
    }

#pragma unroll
    for (int s = 0; s < 8; ++s) {
      sdot[s] += __shfl_xor(sdot[s], 16);
      sdot[s] += __shfl_xor(sdot[s], 32);
    }
    if (quad == 0) {
      fx4 r0, r1;
      r0[0] = sdot[0]; r0[1] = sdot[1]; r0[2] = sdot[2]; r0[3] = sdot[3];
      r1[0] = sdot[4]; r1[1] = sdot[5]; r1[2] = sdot[6]; r1[3] = sdot[7];
      *(fx4*)(s0g + (size_t)node * 4) = r0;
      *(fx4*)(s1g + (size_t)node * 4) = r1;
    }
  }
}

// Stage 1: per-head min/max of att = s0[src] + s1[col]; one thread per 4
// edges (400k threads), block-level reduction, one partial per block.
// (Two-stage tree reverted from R2's device atomics: same-address atomic
// serialization cost ~+21 us.)
__global__ __launch_bounds__(256) void minmax1_kernel(
    const int* __restrict__ cidx, const float* __restrict__ s0g,
    const float* __restrict__ s1g, float* __restrict__ partial)
{
  __shared__ float s_red[4][8];
  const int t = blockIdx.x * 256 + threadIdx.x;
  fx4 mx, mn;
#pragma unroll
  for (int h = 0; h < 4; ++h) { mx[h] = -1e30f; mn[h] = 1e30f; }
  if (t < EE / 4) {
    const int node = t >> 2;  // edges 4t..4t+3 all have src = t>>2
    const fx4 s0v = *(const fx4*)(s0g + (size_t)node * 4);
    const int4 c4 = ((const int4*)cidx)[t];
    const int cc[4] = {c4.x, c4.y, c4.z, c4.w};
#pragma unroll
    for (int j = 0; j < 4; ++j) {
      const fx4 s1v = *(const fx4*)(s1g + (size_t)cc[j] * 4);
#pragma unroll
      for (int h = 0; h < 4; ++h) {
        const float att = s0v[h] + s1v[h];
        mx[h] = fmaxf(mx[h], att);
        mn[h] = fminf(mn[h], att);
      }
    }
  }
#pragma unroll
  for (int off = 1; off < 64; off <<= 1) {
#pragma unroll
    for (int h = 0; h < 4; ++h) {
      mx[h] = fmaxf(mx[h], __shfl_xor(mx[h], off));
      mn[h] = fminf(mn[h], __shfl_xor(mn[h], off));
    }
  }
  const int wv = threadIdx.x >> 6;
  if ((threadIdx.x & 63) == 0) {
#pragma unroll
    for (int h = 0; h < 4; ++h) {
      s_red[wv][h] = mx[h];
      s_red[wv][4 + h] = mn[h];
    }
  }
  __syncthreads();
  if (threadIdx.x < 8) {
    const int s = threadIdx.x;
    float v = s_red[0][s];
    if (s < 4) { v = fmaxf(v, s_red[1][s]); v = fmaxf(v, s_red[2][s]); v = fmaxf(v, s_red[3][s]); }
    else       { v = fminf(v, s_red[1][s]); v = fminf(v, s_red[2][s]); v = fminf(v, s_red[3][s]); }
    partial[blockIdx.x * 8 + s] = v;
  }
}

// Stage 2: one block reduces MM_BLOCKS*8 partials -> mm[8] = {mx[4], mn[4]}.
__global__ __launch_bounds__(256) void minmax2_kernel(
    const float* __restrict__ partial, float* __restrict__ mm)
{
  __shared__ float s_red[4][8];
  fx4 mx, mn;
#pragma unroll
  for (int h = 0; h < 4; ++h) { mx[h] = -1e30f; mn[h] = 1e30f; }
  for (int g = threadIdx.x; g < MM_BLOCKS; g += 256) {
    const fx4 p0 = *(const fx4*)(partial + g * 8);
    const fx4 p1 = *(const fx4*)(partial + g * 8 + 4);
#pragma unroll
    for (int h = 0; h < 4; ++h) {
      mx[h] = fmaxf(mx[h], p0[h]);
      mn[h] = fminf(mn[h], p1[h]);
    }
  }
#pragma unroll
  for (int off = 1; off < 64; off <<= 1) {
#pragma unroll
    for (int h = 0; h < 4; ++h) {
      mx[h] = fmaxf(mx[h], __shfl_xor(mx[h], off));
      mn[h] = fminf(mn[h], __shfl_xor(mn[h], off));
    }
  }
  const int wv = threadIdx.x >> 6;
  if ((threadIdx.x & 63) == 0) {
#pragma unroll
    for (int h = 0; h < 4; ++h) {
      s_red[wv][h] = mx[h];
      s_red[wv][4 + h] = mn[h];
    }
  }
  __syncthreads();
  if (threadIdx.x < 8) {
    const int s = threadIdx.x;
    float v = s_red[0][s];
    if (s < 4) { v = fmaxf(v, s_red[1][s]); v = fmaxf(v, s_red[2][s]); v = fmaxf(v, s_red[3][s]); }
    else       { v = fminf(v, s_red[1][s]); v = fminf(v, s_red[2][s]); v = fminf(v, s_red[3][s]); }
    mm[s] = v;
  }
}

// Per node: weighted aggregation of 16 neighbor F1 rows.
// 16 lanes per node; lane covers 8 consecutive dims (bf16x8 = 16B loads).
// Forced MLP (all 32 gathers issued before sched_barrier(0)): best measured
// config (69.2 us). Two configs (VGPR 36/occ 65% and VGPR 64/occ 37%) both
// land ~70 us @ ~4 TB/s L2-miss traffic -> random-gather fabric ceiling.
__global__ __launch_bounds__(256) void aggregate_kernel(
    const int* __restrict__ cidx, const float* __restrict__ s0g,
    const float* __restrict__ s1g, const bf16_t* __restrict__ F1,
    const float* __restrict__ mm, float* __restrict__ out)
{
  const int t = blockIdx.x * 256 + threadIdx.x;
  const int node = t >> 4;
  if (node >= NN) return;
  const int sub = t & 15;
  const int h = sub >> 2;
  const float mxv = mm[h];
  const float mnv = mm[4 + h];
  const float scale = 1.f / (mxv - mnv);
  const float s0v = s0g[node * 4 + h];
  float a_[8] = {0.f, 0.f, 0.f, 0.f, 0.f, 0.f, 0.f, 0.f};
  float wsum = 0.f;

  const int4* ce4 = (const int4*)(cidx + (size_t)node * 16);
  const int4 c01 = ce4[0], c23 = ce4[1], c45 = ce4[2], c67 = ce4[3];
  const int cc[16] = {c01.x, c01.y, c01.z, c01.w, c23.x, c23.y, c23.z, c23.w,
                      c45.x, c45.y, c45.z, c45.w, c67.x, c67.y, c67.z, c67.w};

  float s1v[16];
  bf16x8 f[16];
#pragma unroll
  for (int j = 0; j < 16; ++j) {
    const int c = cc[j];
    s1v[j] = s1g[(size_t)c * 4 + h];
    f[j] = *(const bf16x8*)(F1 + (size_t)c * 128 + sub * 8);
  }
  __builtin_amdgcn_sched_barrier(0);  // loads may not sink below this point

#pragma unroll
  for (int j = 0; j < 16; ++j) {
    const float w = __expf((s0v + s1v[j] - mnv) * scale);
    wsum += w;
#pragma unroll
    for (int k = 0; k < 8; ++k) a_[k] += w * (float)f[j][k];
  }

  const float inv = 1.f / wsum;
  fx4 r0, r1;
#pragma unroll
  for (int j = 0; j < 4; ++j) { r0[j] = a_[j] * inv; r1[j] = a_[4 + j] * inv; }
  float* op = out + (size_t)node * 128 + sub * 8;
  *(fx4*)op = r0;
  *(fx4*)(op + 4) = r1;
}

extern "C" void kernel_launch(void* const* d_in, const int* in_sizes, int n_in,
                              void* d_out, int out_size, void* d_ws, size_t ws_size,
                              hipStream_t stream)
{
  const float* X   = (const float*)d_in[0];
  const float* W0  = (const float*)d_in[1];
  const float* W1  = (const float*)d_in[2];
  const float* a0  = (const float*)d_in[3];
  // d_in[4] = edge_src: structurally repeat(arange(N),16); use e>>4 instead.
  const int* cidx  = (const int*)d_in[5];
  char* ws = (char*)d_ws;
  uint4*    Wtab    = (uint4*)ws;
  bf16_t*   F1      = (bf16_t*)(ws + 65536);
  float*    s0g     = (float*)(ws + 25665536);
  float*    s1g     = (float*)(ws + 27265536);
  float*    mm      = (float*)(ws + 28865536);
  float*    partial = (float*)(ws + 28865600);
  float*    out     = (float*)d_out;

  wconv_kernel<<<8, 512, 0, stream>>>(W0, W1, Wtab);
  gemm_kernel<<<GEMM_BLOCKS, 512, 0, stream>>>(X, Wtab, a0, F1, s0g, s1g);
  minmax1_kernel<<<MM_BLOCKS, 256, 0, stream>>>(cidx, s0g, s1g, partial);
  minmax2_kernel<<<1, 256, 0, stream>>>(partial, mm);
  aggregate_kernel<<<6250, 256, 0, stream>>>(cidx, s0g, s1g, F1, mm, out);
}

// Round 4
// 209.681 us; speedup vs baseline: 1.0809x; 1.0120x over previous
//
#include <hip/hip_runtime.h>
#include <hip/hip_bf16.h>
#include <stdint.h>

#define NN 100000
#define EE 1600000
#define ALPHA 0.2f
#define MM1_BLOCKS 391  // ceil(400000/1024)

typedef __bf16 bf16_t;
typedef __bf16 bf16x8 __attribute__((ext_vector_type(8)));
typedef __bf16 bf16x4 __attribute__((ext_vector_type(4)));
typedef float fx4 __attribute__((ext_vector_type(4)));

// ---- workspace layout (bytes) ----
// Wtab    @ 0         : 4096 uint4 (64 KB) frag-major bf16 W0|W1 table
// F1      @ 65536     : 100000*128 bf16     = 25600000
// s0      @ 25665536  : 100000*4  f32       = 1600000
// s1      @ 27265536  : 100000*4  f32       = 1600000
// partial @ 28865600  : MM1_BLOCKS*8 f32    = 12512

// One-shot: build the fragment-major lane-linear bf16 W table in global WS.
// task: ct=task>>8, ks=(task>>6)&3, l=task&63; W row = ct*16+(l&15),
// float col0 = (ks*4+(l>>4))*8.  Wtab[task] = 8 bf16 (16 B).
__global__ __launch_bounds__(512) void wconv_kernel(
    const float* __restrict__ W0, const float* __restrict__ W1,
    uint4* __restrict__ Wtab)
{
  const int task = blockIdx.x * 512 + threadIdx.x;
  if (task >= 4096) return;
  const int sct = task >> 8, sks = (task >> 6) & 3, sl = task & 63;
  const int r  = sct * 16 + (sl & 15);
  const int c0 = (sks * 4 + (sl >> 4)) * 8;
  const float* src = (r < 128 ? W0 + (size_t)r * 128 : W1 + (size_t)(r - 128) * 128) + c0;
  const fx4 wa = *(const fx4*)src;
  const fx4 wb = *(const fx4*)(src + 4);
  bf16x8 wf;
  wf[0] = (bf16_t)wa[0]; wf[1] = (bf16_t)wa[1];
  wf[2] = (bf16_t)wa[2]; wf[3] = (bf16_t)wa[3];
  wf[4] = (bf16_t)wb[0]; wf[5] = (bf16_t)wb[1];
  wf[6] = (bf16_t)wb[2]; wf[7] = (bf16_t)wb[3];
  Wtab[task] = __builtin_bit_cast(uint4, wf);
}

// One wave per 16-node tile, 8 tiles per 512-thread block (782 blocks —
// grid-stride reverted: 391 blocks gave ~1.5x CU load imbalance, -5us).
// Whole 64 KB bf16 W table async-DMA'd into LDS (global_load_lds, 16 B/lane,
// lane-linear). D[ch][node] = leaky(W_ch . X_node) via mfma(wf, xf);
// ch=ct*16+quad*4+r, node=n0+col. 64 KB LDS + 512 thr -> 2 blocks/CU.
__global__ __launch_bounds__(512) void gemm_kernel(
    const float* __restrict__ X, const uint4* __restrict__ Wtab,
    const float* __restrict__ a0,
    bf16_t* __restrict__ F1, float* __restrict__ s0g, float* __restrict__ s1g)
{
  __shared__ uint4 lw[4096];  // 64 KB
  const int tid  = threadIdx.x;
  const int wv   = tid >> 6;
  const int lane = tid & 63;
  const int col  = lane & 15;
  const int quad = lane >> 4;

  // Async-stage the precomputed table: per wave, dest = uniform base +
  // lane*16 which matches task = i*512 + wv*64 + lane exactly.
  // NOTE: must run before any early return — each wave stages its own slice.
#pragma unroll
  for (int i = 0; i < 8; ++i) {
    const int task = i * 512 + tid;
    __builtin_amdgcn_global_load_lds(
        (const __attribute__((address_space(1))) uint32_t*)(Wtab + task),
        (__attribute__((address_space(3))) uint32_t*)(&lw[task]), 16, 0, 0);
  }
  __syncthreads();  // emits s_waitcnt vmcnt(0) before s_barrier -> DMA done

  const int tile = blockIdx.x * 8 + wv;
  if (tile >= (NN / 16)) return;
  const int n0   = tile * 16;
  const int node = n0 + col;

  fx4 acc[16];
#pragma unroll
  for (int c = 0; c < 16; ++c) {
    acc[c][0] = 0.f; acc[c][1] = 0.f; acc[c][2] = 0.f; acc[c][3] = 0.f;
  }

  const float* xrow = X + (size_t)node * 128 + quad * 8;
#pragma unroll
  for (int ks = 0; ks < 4; ++ks) {
    fx4 xa = *(const fx4*)(xrow + ks * 32);
    fx4 xb = *(const fx4*)(xrow + ks * 32 + 4);
    bf16x8 xf;
    xf[0] = (bf16_t)xa[0]; xf[1] = (bf16_t)xa[1];
    xf[2] = (bf16_t)xa[2]; xf[3] = (bf16_t)xa[3];
    xf[4] = (bf16_t)xb[0]; xf[5] = (bf16_t)xb[1];
    xf[6] = (bf16_t)xb[2]; xf[7] = (bf16_t)xb[3];
#pragma unroll
    for (int ct = 0; ct < 16; ++ct) {
      const uint4 w4 = lw[(ct * 4 + ks) * 64 + lane];
      const bf16x8 wf = __builtin_bit_cast(bf16x8, w4);
      acc[ct] = __builtin_amdgcn_mfma_f32_16x16x32_bf16(wf, xf, acc[ct], 0, 0, 0);
    }
  }

  float sdot[8];
#pragma unroll
  for (int s = 0; s < 8; ++s) sdot[s] = 0.f;

#pragma unroll
  for (int ct = 0; ct < 16; ++ct) {
    const fx4 av = *(const fx4*)(a0 + (ct & 7) * 16 + quad * 4);
#pragma unroll
    for (int r = 0; r < 4; ++r) {
      float v = acc[ct][r];
      v = v > 0.f ? v : ALPHA * v;
      acc[ct][r] = v;
      sdot[ct >> 1] += v * av[r];
    }
    if (ct >= 8) {
      bf16x4 p;
      p[0] = (bf16_t)acc[ct][0]; p[1] = (bf16_t)acc[ct][1];
      p[2] = (bf16_t)acc[ct][2]; p[3] = (bf16_t)acc[ct][3];
      *(bf16x4*)(F1 + (size_t)node * 128 + (ct - 8) * 16 + quad * 4) = p;
    }
  }

#pragma unroll
  for (int s = 0; s < 8; ++s) {
    sdot[s] += __shfl_xor(sdot[s], 16);
    sdot[s] += __shfl_xor(sdot[s], 32);
  }
  if (quad == 0) {
    fx4 r0, r1;
    r0[0] = sdot[0]; r0[1] = sdot[1]; r0[2] = sdot[2]; r0[3] = sdot[3];
    r1[0] = sdot[4]; r1[1] = sdot[5]; r1[2] = sdot[6]; r1[3] = sdot[7];
    *(fx4*)(s0g + (size_t)node * 4) = r0;
    *(fx4*)(s1g + (size_t)node * 4) = r1;
  }
}

// Stage 1: per-head min/max of att = s0[src] + s1[col]; one thread per 4
// edges, 1024-thread blocks (391 blocks -> partial buffer is only 12.5 KB,
// small enough for every aggregate block to re-reduce it inline).
__global__ __launch_bounds__(1024) void minmax1_kernel(
    const int* __restrict__ cidx, const float* __restrict__ s0g,
    const float* __restrict__ s1g, float* __restrict__ partial)
{
  __shared__ float s_red[16][8];
  const int t = blockIdx.x * 1024 + threadIdx.x;
  fx4 mx, mn;
#pragma unroll
  for (int h = 0; h < 4; ++h) { mx[h] = -1e30f; mn[h] = 1e30f; }
  if (t < EE / 4) {
    const int node = t >> 2;  // edges 4t..4t+3 all have src = t>>2
    const fx4 s0v = *(const fx4*)(s0g + (size_t)node * 4);
    const int4 c4 = ((const int4*)cidx)[t];
    const int cc[4] = {c4.x, c4.y, c4.z, c4.w};
#pragma unroll
    for (int j = 0; j < 4; ++j) {
      const fx4 s1v = *(const fx4*)(s1g + (size_t)cc[j] * 4);
#pragma unroll
      for (int h = 0; h < 4; ++h) {
        const float att = s0v[h] + s1v[h];
        mx[h] = fmaxf(mx[h], att);
        mn[h] = fminf(mn[h], att);
      }
    }
  }
#pragma unroll
  for (int off = 1; off < 64; off <<= 1) {
#pragma unroll
    for (int h = 0; h < 4; ++h) {
      mx[h] = fmaxf(mx[h], __shfl_xor(mx[h], off));
      mn[h] = fminf(mn[h], __shfl_xor(mn[h], off));
    }
  }
  const int wv = threadIdx.x >> 6;
  if ((threadIdx.x & 63) == 0) {
#pragma unroll
    for (int h = 0; h < 4; ++h) {
      s_red[wv][h] = mx[h];
      s_red[wv][4 + h] = mn[h];
    }
  }
  __syncthreads();
  if (threadIdx.x < 8) {
    const int s = threadIdx.x;
    float v = s_red[0][s];
    if (s < 4) {
#pragma unroll
      for (int w = 1; w < 16; ++w) v = fmaxf(v, s_red[w][s]);
    } else {
#pragma unroll
      for (int w = 1; w < 16; ++w) v = fminf(v, s_red[w][s]);
    }
    partial[blockIdx.x * 8 + s] = v;
  }
}

// Per node: weighted aggregation of 16 neighbor F1 rows.
// Prologue: every block re-reduces the 12.5 KB partial buffer to mm[8]
// (replaces the minmax2 kernel + one launch gap; ~78 MB of L2 broadcast
// across the grid ~ +1.5us on this kernel).
// Gather body: forced MLP (32 gathers before sched_barrier(0)); measured
// fabric ceiling ~70us @ ~4 TB/s L2-fill on random 256-B reads.
__global__ __launch_bounds__(256) void aggregate_kernel(
    const int* __restrict__ cidx, const float* __restrict__ s0g,
    const float* __restrict__ s1g, const bf16_t* __restrict__ F1,
    const float* __restrict__ partial, float* __restrict__ out)
{
  __shared__ float s_mm[8];
  __shared__ float s_red[4][8];
  {
    fx4 mx, mn;
#pragma unroll
    for (int h = 0; h < 4; ++h) { mx[h] = -1e30f; mn[h] = 1e30f; }
    for (int g = threadIdx.x; g < MM1_BLOCKS; g += 256) {
      const fx4 p0 = *(const fx4*)(partial + g * 8);
      const fx4 p1 = *(const fx4*)(partial + g * 8 + 4);
#pragma unroll
      for (int h = 0; h < 4; ++h) {
        mx[h] = fmaxf(mx[h], p0[h]);
        mn[h] = fminf(mn[h], p1[h]);
      }
    }
#pragma unroll
    for (int off = 1; off < 64; off <<= 1) {
#pragma unroll
      for (int h = 0; h < 4; ++h) {
        mx[h] = fmaxf(mx[h], __shfl_xor(mx[h], off));
        mn[h] = fminf(mn[h], __shfl_xor(mn[h], off));
      }
    }
    const int wv = threadIdx.x >> 6;
    if ((threadIdx.x & 63) == 0) {
#pragma unroll
      for (int h = 0; h < 4; ++h) {
        s_red[wv][h] = mx[h];
        s_red[wv][4 + h] = mn[h];
      }
    }
    __syncthreads();
    if (threadIdx.x < 8) {
      const int s = threadIdx.x;
      float v = s_red[0][s];
      if (s < 4) { v = fmaxf(v, s_red[1][s]); v = fmaxf(v, s_red[2][s]); v = fmaxf(v, s_red[3][s]); }
      else       { v = fminf(v, s_red[1][s]); v = fminf(v, s_red[2][s]); v = fminf(v, s_red[3][s]); }
      s_mm[s] = v;
    }
    __syncthreads();
  }

  const int t = blockIdx.x * 256 + threadIdx.x;
  const int node = t >> 4;
  if (node >= NN) return;
  const int sub = t & 15;
  const int h = sub >> 2;
  const float mxv = s_mm[h];
  const float mnv = s_mm[4 + h];
  const float scale = 1.f / (mxv - mnv);
  const float s0v = s0g[node * 4 + h];
  float a_[8] = {0.f, 0.f, 0.f, 0.f, 0.f, 0.f, 0.f, 0.f};
  float wsum = 0.f;

  const int4* ce4 = (const int4*)(cidx + (size_t)node * 16);
  const int4 c01 = ce4[0], c23 = ce4[1], c45 = ce4[2], c67 = ce4[3];
  const int cc[16] = {c01.x, c01.y, c01.z, c01.w, c23.x, c23.y, c23.z, c23.w,
                      c45.x, c45.y, c45.z, c45.w, c67.x, c67.y, c67.z, c67.w};

  float s1v[16];
  bf16x8 f[16];
#pragma unroll
  for (int j = 0; j < 16; ++j) {
    const int c = cc[j];
    s1v[j] = s1g[(size_t)c * 4 + h];
    f[j] = *(const bf16x8*)(F1 + (size_t)c * 128 + sub * 8);
  }
  __builtin_amdgcn_sched_barrier(0);  // loads may not sink below this point

#pragma unroll
  for (int j = 0; j < 16; ++j) {
    const float w = __expf((s0v + s1v[j] - mnv) * scale);
    wsum += w;
#pragma unroll
    for (int k = 0; k < 8; ++k) a_[k] += w * (float)f[j][k];
  }

  const float inv = 1.f / wsum;
  fx4 r0, r1;
#pragma unroll
  for (int j = 0; j < 4; ++j) { r0[j] = a_[j] * inv; r1[j] = a_[4 + j] * inv; }
  float* op = out + (size_t)node * 128 + sub * 8;
  *(fx4*)op = r0;
  *(fx4*)(op + 4) = r1;
}

extern "C" void kernel_launch(void* const* d_in, const int* in_sizes, int n_in,
                              void* d_out, int out_size, void* d_ws, size_t ws_size,
                              hipStream_t stream)
{
  const float* X   = (const float*)d_in[0];
  const float* W0  = (const float*)d_in[1];
  const float* W1  = (const float*)d_in[2];
  const float* a0  = (const float*)d_in[3];
  // d_in[4] = edge_src: structurally repeat(arange(N),16); use e>>4 instead.
  const int* cidx  = (const int*)d_in[5];
  char* ws = (char*)d_ws;
  uint4*    Wtab    = (uint4*)ws;
  bf16_t*   F1      = (bf16_t*)(ws + 65536);
  float*    s0g     = (float*)(ws + 25665536);
  float*    s1g     = (float*)(ws + 27265536);
  float*    partial = (float*)(ws + 28865600);
  float*    out     = (float*)d_out;

  wconv_kernel<<<8, 512, 0, stream>>>(W0, W1, Wtab);
  gemm_kernel<<<782, 512, 0, stream>>>(X, Wtab, a0, F1, s0g, s1g);
  minmax1_kernel<<<MM1_BLOCKS, 1024, 0, stream>>>(cidx, s0g, s1g, partial);
  aggregate_kernel<<<6250, 256, 0, stream>>>(cidx, s0g, s1g, F1, partial, out);
}

// Round 6
// 207.069 us; speedup vs baseline: 1.0945x; 1.0126x over previous
//
#include <hip/hip_runtime.h>
#include <hip/hip_bf16.h>
#include <stdint.h>

#define NN 100000
#define EE 1600000
#define ALPHA 0.2f
#define MM1_BLOCKS 391  // ceil(400000/1024)

typedef __bf16 bf16_t;
typedef __bf16 bf16x8 __attribute__((ext_vector_type(8)));
typedef __bf16 bf16x4 __attribute__((ext_vector_type(4)));
typedef float fx4 __attribute__((ext_vector_type(4)));

// ---- workspace layout (bytes) ----
// Wtab    @ 0         : 4096 uint4 (64 KB) frag-major bf16 W0|W1 table
// F1      @ 65536     : 100000*128 bf16     = 25600000
// s0      @ 25665536  : 100000*4  f32       = 1600000
// s1      @ 27265536  : 100000*4  f32       = 1600000
// mm      @ 28865536  : 8 f32 (mx[4], mn[4])
// partial @ 28865600  : MM1_BLOCKS*8 f32    = 12512

// One-shot: build the fragment-major lane-linear bf16 W table in global WS.
// task: ct=task>>8, ks=(task>>6)&3, l=task&63; W row = ct*16+(l&15),
// float col0 = (ks*4+(l>>4))*8.  Wtab[task] = 8 bf16 (16 B).
__global__ __launch_bounds__(512) void wconv_kernel(
    const float* __restrict__ W0, const float* __restrict__ W1,
    uint4* __restrict__ Wtab)
{
  const int task = blockIdx.x * 512 + threadIdx.x;
  if (task >= 4096) return;
  const int sct = task >> 8, sks = (task >> 6) & 3, sl = task & 63;
  const int r  = sct * 16 + (sl & 15);
  const int c0 = (sks * 4 + (sl >> 4)) * 8;
  const float* src = (r < 128 ? W0 + (size_t)r * 128 : W1 + (size_t)(r - 128) * 128) + c0;
  const fx4 wa = *(const fx4*)src;
  const fx4 wb = *(const fx4*)(src + 4);
  bf16x8 wf;
  wf[0] = (bf16_t)wa[0]; wf[1] = (bf16_t)wa[1];
  wf[2] = (bf16_t)wa[2]; wf[3] = (bf16_t)wa[3];
  wf[4] = (bf16_t)wb[0]; wf[5] = (bf16_t)wb[1];
  wf[6] = (bf16_t)wb[2]; wf[7] = (bf16_t)wb[3];
  Wtab[task] = __builtin_bit_cast(uint4, wf);
}

// One wave per 16-node tile, 8 tiles per 512-thread block (782 blocks).
// Whole 64 KB bf16 W table async-DMA'd into LDS (global_load_lds, 16 B/lane,
// lane-linear). D[ch][node] = leaky(W_ch . X_node) via mfma(wf, xf);
// ch=ct*16+quad*4+r, node=n0+col. 64 KB LDS + 512 thr -> 2 blocks/CU.
__global__ __launch_bounds__(512) void gemm_kernel(
    const float* __restrict__ X, const uint4* __restrict__ Wtab,
    const float* __restrict__ a0,
    bf16_t* __restrict__ F1, float* __restrict__ s0g, float* __restrict__ s1g)
{
  __shared__ uint4 lw[4096];  // 64 KB
  const int tid  = threadIdx.x;
  const int wv   = tid >> 6;
  const int lane = tid & 63;
  const int col  = lane & 15;
  const int quad = lane >> 4;

#pragma unroll
  for (int i = 0; i < 8; ++i) {
    const int task = i * 512 + tid;
    __builtin_amdgcn_global_load_lds(
        (const __attribute__((address_space(1))) uint32_t*)(Wtab + task),
        (__attribute__((address_space(3))) uint32_t*)(&lw[task]), 16, 0, 0);
  }
  __syncthreads();  // emits s_waitcnt vmcnt(0) before s_barrier -> DMA done

  const int tile = blockIdx.x * 8 + wv;
  if (tile >= (NN / 16)) return;
  const int n0   = tile * 16;
  const int node = n0 + col;

  fx4 acc[16];
#pragma unroll
  for (int c = 0; c < 16; ++c) {
    acc[c][0] = 0.f; acc[c][1] = 0.f; acc[c][2] = 0.f; acc[c][3] = 0.f;
  }

  const float* xrow = X + (size_t)node * 128 + quad * 8;
#pragma unroll
  for (int ks = 0; ks < 4; ++ks) {
    fx4 xa = *(const fx4*)(xrow + ks * 32);
    fx4 xb = *(const fx4*)(xrow + ks * 32 + 4);
    bf16x8 xf;
    xf[0] = (bf16_t)xa[0]; xf[1] = (bf16_t)xa[1];
    xf[2] = (bf16_t)xa[2]; xf[3] = (bf16_t)xa[3];
    xf[4] = (bf16_t)xb[0]; xf[5] = (bf16_t)xb[1];
    xf[6] = (bf16_t)xb[2]; xf[7] = (bf16_t)xb[3];
#pragma unroll
    for (int ct = 0; ct < 16; ++ct) {
      const uint4 w4 = lw[(ct * 4 + ks) * 64 + lane];
      const bf16x8 wf = __builtin_bit_cast(bf16x8, w4);
      acc[ct] = __builtin_amdgcn_mfma_f32_16x16x32_bf16(wf, xf, acc[ct], 0, 0, 0);
    }
  }

  float sdot[8];
#pragma unroll
  for (int s = 0; s < 8; ++s) sdot[s] = 0.f;

#pragma unroll
  for (int ct = 0; ct < 16; ++ct) {
    const fx4 av = *(const fx4*)(a0 + (ct & 7) * 16 + quad * 4);
#pragma unroll
    for (int r = 0; r < 4; ++r) {
      float v = acc[ct][r];
      v = v > 0.f ? v : ALPHA * v;
      acc[ct][r] = v;
      sdot[ct >> 1] += v * av[r];
    }
    if (ct >= 8) {
      bf16x4 p;
      p[0] = (bf16_t)acc[ct][0]; p[1] = (bf16_t)acc[ct][1];
      p[2] = (bf16_t)acc[ct][2]; p[3] = (bf16_t)acc[ct][3];
      *(bf16x4*)(F1 + (size_t)node * 128 + (ct - 8) * 16 + quad * 4) = p;
    }
  }

#pragma unroll
  for (int s = 0; s < 8; ++s) {
    sdot[s] += __shfl_xor(sdot[s], 16);
    sdot[s] += __shfl_xor(sdot[s], 32);
  }
  if (quad == 0) {
    fx4 r0, r1;
    r0[0] = sdot[0]; r0[1] = sdot[1]; r0[2] = sdot[2]; r0[3] = sdot[3];
    r1[0] = sdot[4]; r1[1] = sdot[5]; r1[2] = sdot[6]; r1[3] = sdot[7];
    *(fx4*)(s0g + (size_t)node * 4) = r0;
    *(fx4*)(s1g + (size_t)node * 4) = r1;
  }
}

// Stage 1: per-head min/max of att = s0[src] + s1[col]; one thread per 4
// edges, 1024-thread blocks -> 391 partials.
__global__ __launch_bounds__(1024) void minmax1_kernel(
    const int* __restrict__ cidx, const float* __restrict__ s0g,
    const float* __restrict__ s1g, float* __restrict__ partial)
{
  __shared__ float s_red[16][8];
  const int t = blockIdx.x * 1024 + threadIdx.x;
  fx4 mx, mn;
#pragma unroll
  for (int h = 0; h < 4; ++h) { mx[h] = -1e30f; mn[h] = 1e30f; }
  if (t < EE / 4) {
    const int node = t >> 2;  // edges 4t..4t+3 all have src = t>>2
    const fx4 s0v = *(const fx4*)(s0g + (size_t)node * 4);
    const int4 c4 = ((const int4*)cidx)[t];
    const int cc[4] = {c4.x, c4.y, c4.z, c4.w};
#pragma unroll
    for (int j = 0; j < 4; ++j) {
      const fx4 s1v = *(const fx4*)(s1g + (size_t)cc[j] * 4);
#pragma unroll
      for (int h = 0; h < 4; ++h) {
        const float att = s0v[h] + s1v[h];
        mx[h] = fmaxf(mx[h], att);
        mn[h] = fminf(mn[h], att);
      }
    }
  }
#pragma unroll
  for (int off = 1; off < 64; off <<= 1) {
#pragma unroll
    for (int h = 0; h < 4; ++h) {
      mx[h] = fmaxf(mx[h], __shfl_xor(mx[h], off));
      mn[h] = fminf(mn[h], __shfl_xor(mn[h], off));
    }
  }
  const int wv = threadIdx.x >> 6;
  if ((threadIdx.x & 63) == 0) {
#pragma unroll
    for (int h = 0; h < 4; ++h) {
      s_red[wv][h] = mx[h];
      s_red[wv][4 + h] = mn[h];
    }
  }
  __syncthreads();
  if (threadIdx.x < 8) {
    const int s = threadIdx.x;
    float v = s_red[0][s];
    if (s < 4) {
#pragma unroll
      for (int w = 1; w < 16; ++w) v = fmaxf(v, s_red[w][s]);
    } else {
#pragma unroll
      for (int w = 1; w < 16; ++w) v = fminf(v, s_red[w][s]);
    }
    partial[blockIdx.x * 8 + s] = v;
  }
}

// Stage 2: one block reduces MM1_BLOCKS*8 partials -> mm[8] = {mx[4], mn[4]}.
// (Restored: R4's per-block inline re-reduce cost +6.6us on aggregate vs
// ~4us saved by dropping this kernel — net regression.)
__global__ __launch_bounds__(256) void minmax2_kernel(
    const float* __restrict__ partial, float* __restrict__ mm)
{
  __shared__ float s_red[4][8];
  fx4 mx, mn;
#pragma unroll
  for (int h = 0; h < 4; ++h) { mx[h] = -1e30f; mn[h] = 1e30f; }
  for (int g = threadIdx.x; g < MM1_BLOCKS; g += 256) {
    const fx4 p0 = *(const fx4*)(partial + g * 8);
    const fx4 p1 = *(const fx4*)(partial + g * 8 + 4);
#pragma unroll
    for (int h = 0; h < 4; ++h) {
      mx[h] = fmaxf(mx[h], p0[h]);
      mn[h] = fminf(mn[h], p1[h]);
    }
  }
#pragma unroll
  for (int off = 1; off < 64; off <<= 1) {
#pragma unroll
    for (int h = 0; h < 4; ++h) {
      mx[h] = fmaxf(mx[h], __shfl_xor(mx[h], off));
      mn[h] = fminf(mn[h], __shfl_xor(mn[h], off));
    }
  }
  const int wv = threadIdx.x >> 6;
  if ((threadIdx.x & 63) == 0) {
#pragma unroll
    for (int h = 0; h < 4; ++h) {
      s_red[wv][h] = mx[h];
      s_red[wv][4 + h] = mn[h];
    }
  }
  __syncthreads();
  if (threadIdx.x < 8) {
    const int s = threadIdx.x;
    float v = s_red[0][s];
    if (s < 4) { v = fmaxf(v, s_red[1][s]); v = fmaxf(v, s_red[2][s]); v = fmaxf(v, s_red[3][s]); }
    else       { v = fminf(v, s_red[1][s]); v = fminf(v, s_red[2][s]); v = fminf(v, s_red[3][s]); }
    mm[s] = v;
  }
}

// Per node: weighted aggregation of 16 neighbor F1 rows.
// SPLIT into two half-node launches (node_base param) as a measurement
// probe: each half ~35us, so any kernel >35us (gemm!) surfaces in the
// rocprof top-5 with full counters. Direct mm[] reads (prologue removed).
// Gather body: forced MLP (32 gathers before sched_barrier(0)); measured
// fabric ceiling ~70us total @ ~4 TB/s on random 256-B reads.
__global__ __launch_bounds__(256) void aggregate_kernel(
    const int* __restrict__ cidx, const float* __restrict__ s0g,
    const float* __restrict__ s1g, const bf16_t* __restrict__ F1,
    const float* __restrict__ mm, float* __restrict__ out, int node_base)
{
  const int t = blockIdx.x * 256 + threadIdx.x;
  const int node = node_base + (t >> 4);
  if (node >= NN) return;
  const int sub = t & 15;
  const int h = sub >> 2;
  const float mxv = mm[h];
  const float mnv = mm[4 + h];
  const float scale = 1.f / (mxv - mnv);
  const float s0v = s0g[node * 4 + h];
  float a_[8] = {0.f, 0.f, 0.f, 0.f, 0.f, 0.f, 0.f, 0.f};
  float wsum = 0.f;

  const int4* ce4 = (const int4*)(cidx + (size_t)node * 16);
  const int4 c01 = ce4[0], c23 = ce4[1], c45 = ce4[2], c67 = ce4[3];
  const int cc[16] = {c01.x, c01.y, c01.z, c01.w, c23.x, c23.y, c23.z, c23.w,
                      c45.x, c45.y, c45.z, c45.w, c67.x, c67.y, c67.z, c67.w};

  float s1v[16];
  bf16x8 f[16];
#pragma unroll
  for (int j = 0; j < 16; ++j) {
    const int c = cc[j];
    s1v[j] = s1g[(size_t)c * 4 + h];
    f[j] = *(const bf16x8*)(F1 + (size_t)c * 128 + sub * 8);
  }
  __builtin_amdgcn_sched_barrier(0);  // loads may not sink below this point

#pragma unroll
  for (int j = 0; j < 16; ++j) {
    const float w = __expf((s0v + s1v[j] - mnv) * scale);
    wsum += w;
#pragma unroll
    for (int k = 0; k < 8; ++k) a_[k] += w * (float)f[j][k];
  }

  const float inv = 1.f / wsum;
  fx4 r0, r1;
#pragma unroll
  for (int j = 0; j < 4; ++j) { r0[j] = a_[j] * inv; r1[j] = a_[4 + j] * inv; }
  float* op = out + (size_t)node * 128 + sub * 8;
  *(fx4*)op = r0;
  *(fx4*)(op + 4) = r1;
}

extern "C" void kernel_launch(void* const* d_in, const int* in_sizes, int n_in,
                              void* d_out, int out_size, void* d_ws, size_t ws_size,
                              hipStream_t stream)
{
  const float* X   = (const float*)d_in[0];
  const float* W0  = (const float*)d_in[1];
  const float* W1  = (const float*)d_in[2];
  const float* a0  = (const float*)d_in[3];
  // d_in[4] = edge_src: structurally repeat(arange(N),16); use e>>4 instead.
  const int* cidx  = (const int*)d_in[5];
  char* ws = (char*)d_ws;
  uint4*    Wtab    = (uint4*)ws;
  bf16_t*   F1      = (bf16_t*)(ws + 65536);
  float*    s0g     = (float*)(ws + 25665536);
  float*    s1g     = (float*)(ws + 27265536);
  float*    mm      = (float*)(ws + 28865536);
  float*    partial = (float*)(ws + 28865600);
  float*    out     = (float*)d_out;

  wconv_kernel<<<8, 512, 0, stream>>>(W0, W1, Wtab);
  gemm_kernel<<<782, 512, 0, stream>>>(X, Wtab, a0, F1, s0g, s1g);
  minmax1_kernel<<<MM1_BLOCKS, 1024, 0, stream>>>(cidx, s0g, s1g, partial);
  minmax2_kernel<<<1, 256, 0, stream>>>(partial, mm);
  aggregate_kernel<<<3125, 256, 0, stream>>>(cidx, s0g, s1g, F1, mm, out, 0);
  aggregate_kernel<<<3125, 256, 0, stream>>>(cidx, s0g, s1g, F1, mm, out, 50000);
}